// Round 8
// baseline (176.423 us; speedup 1.0000x reference)
//
#include <hip/hip_runtime.h>
#include <hip/hip_bf16.h>

// out = (Q K^T) V * scale, softmax discarded => associativity:
//   out_i = Q_i @ (K_i^T @ V_i) * scale over 32 blocks of 2048 flat rows of
//   the (65536,64) view of the (4096,1024) projections.
// R18 = R17 (124.9us, passing) + last-arriver T-reduce:
//   KV blocks count arrivals on cnt[bx] (single acq_rel atomic, NO polling --
//   R12's proven fence machinery minus the spin). The 16th arriver reduces
//   P[bx] (16 chunks f32) -> TB[bx] bf16 row-major. qT_fused's prologue then
//   stages TB[i] via 2 gl_lds16 (R10-verbatim) instead of redundantly
//   re-summing 256 KB x512 blocks (134 MB -> 9 MB).
// 3 kernels: cvt (also zeroes cnt) -> qkvkt768 -> qT_fused.

#define E_DIM 1024
#define N_ROWS 4096

typedef __attribute__((ext_vector_type(8))) short bf16x8;
typedef __attribute__((ext_vector_type(4))) float f32x4;

// ---- ws layout ----
// shorts: QB 0 (Q bf16, 8.4MB)  XB 12582912  WB 16777216  TB 24117504
// floats: P 9961472 (32 blk x 16 chunks x 4096, [d][e]) = 8 MB, ends 12058624
//         BAR 12058624 (32 u32 arrival counters)
#define QB_U 0
#define XB_U 12582912
#define WB_U 16777216
#define TB_U 24117504
#define P_F  9961472
#define BAR_F 12058624

__device__ __forceinline__ unsigned short f2b(float f) {
    union { float f; unsigned int i; } c; c.f = f;
    unsigned int r = c.i + 0x7FFFu + ((c.i >> 16) & 1u);   // RNE (finite data)
    return (unsigned short)(r >> 16);
}

__device__ __forceinline__ uint4 pack8(const f32x4 a, const f32x4 b) {
    uint4 o;
    o.x = (unsigned)f2b(a[0]) | ((unsigned)f2b(a[1]) << 16);
    o.y = (unsigned)f2b(a[2]) | ((unsigned)f2b(a[3]) << 16);
    o.z = (unsigned)f2b(b[0]) | ((unsigned)f2b(b[1]) << 16);
    o.w = (unsigned)f2b(b[2]) | ((unsigned)f2b(b[3]) << 16);
    return o;
}

// pack 4 acc rows + bias into 4 bf16 (one uint2)
__device__ __forceinline__ uint2 packfrag(const f32x4 a, float b) {
    uint2 v;
    v.x = (unsigned)f2b(a[0] + b) | ((unsigned)f2b(a[1] + b) << 16);
    v.y = (unsigned)f2b(a[2] + b) | ((unsigned)f2b(a[3] + b) << 16);
    return v;
}

typedef __attribute__((address_space(1))) const void* gptr_t;
typedef __attribute__((address_space(3))) void* lptr_t;
__device__ __forceinline__ void gl_lds16(const void* g, void* l) {
    __builtin_amdgcn_global_load_lds((gptr_t)g, (lptr_t)l, 16, 0, 0);
}

// swizzled index into a [row][64] LDS tile (8 slots of 8 elems per row)
__device__ __forceinline__ int sw_idx(int row, int r) {
    return row * 64 + (((((r) >> 3) & 7) ^ (row & 7)) << 3) + (r & 7);
}

// swizzled index into a [row][128] LDS tile (16 slots of 8; XOR low 3 slot bits)
__device__ __forceinline__ int sw128(int row, int r) {
    return row * 128 + ((((r >> 3) ^ (row & 7)) & 15) << 3) + (r & 7);
}

// ---------------------------------------------------------------------------
// Kernel 0: fp32 -> bf16 convert: x (4 MB-segs) + Wq/Wk/Wv. Zeroes cnt[32].
// ---------------------------------------------------------------------------
__global__ __launch_bounds__(256) void cvt_bf16(
    const float* __restrict__ x,  const float* __restrict__ wq,
    const float* __restrict__ wk, const float* __restrict__ wv,
    unsigned short* __restrict__ dst0, unsigned* __restrict__ cnt)
{
    if (blockIdx.x == 0 && blockIdx.y == 0 && threadIdx.x < 32)
        cnt[threadIdx.x] = 0u;
    const int seg = blockIdx.y;
    const float* __restrict__ src;
    unsigned short* __restrict__ dst;
    if (seg < 4) { src = x + (size_t)seg * 1048576; dst = dst0 + (size_t)seg * 1048576; }
    else {
        src = (seg == 4) ? wq : (seg == 5) ? wk : wv;
        dst = dst0 + 4194304 + (size_t)(seg - 4) * 1048576;
    }
    const int i = blockIdx.x * 256 + threadIdx.x;   // 0..131071
    const float4 a = *(const float4*)(src + (size_t)i * 8);
    const float4 b = *(const float4*)(src + (size_t)i * 8 + 4);
    uint4 o;
    o.x = (unsigned)f2b(a.x) | ((unsigned)f2b(a.y) << 16);
    o.y = (unsigned)f2b(a.z) | ((unsigned)f2b(a.w) << 16);
    o.z = (unsigned)f2b(b.x) | ((unsigned)f2b(b.y) << 16);
    o.w = (unsigned)f2b(b.z) | ((unsigned)f2b(b.w) << 16);
    *(uint4*)(dst + (size_t)i * 8) = o;
}

// ---------------------------------------------------------------------------
// One full 128x128 K=1024 GEMM accumulation loop (R10 body). acc += Xb@W^T.
// ---------------------------------------------------------------------------
__device__ __forceinline__ void gemm_loop(
    const unsigned short* __restrict__ Xb, const unsigned short* __restrict__ W,
    unsigned short* Als, unsigned short* Bls,
    int m0, int n0, int w, int lane, f32x4 (&acc)[4][4])
{
    const int quad = lane >> 4;
    const int fm   = lane & 15;
    const int sw8  = fm & 7;
    const int srow = lane >> 3;                       // 0..7
    const int skc  = ((lane & 7) ^ (lane >> 3)) * 8;  // swizzled global chunk
    const int wm = (w >> 1) * 64;
    const int wn = (w & 1) * 64;

    for (int k0 = 0; k0 < E_DIM; k0 += 64) {
        #pragma unroll
        for (int c = 0; c < 4; ++c) {
            const int r = w * 32 + c * 8;
            gl_lds16((const void*)(Xb + (size_t)(m0 + r + srow) * E_DIM + k0 + skc),
                     (void*)((char*)Als + r * 128 + lane * 16));
            gl_lds16((const void*)(W + (size_t)(n0 + r + srow) * E_DIM + k0 + skc),
                     (void*)((char*)Bls + r * 128 + lane * 16));
        }
        __syncthreads();

        #pragma unroll
        for (int kk = 0; kk < 2; ++kk) {
            const int slot = ((kk * 4 + quad) ^ sw8) * 8;
            bf16x8 af[4], bf[4];
            #pragma unroll
            for (int t = 0; t < 4; ++t) {
                af[t] = *(const bf16x8*)(Als + (wm + t * 16 + fm) * 64 + slot);
                bf[t] = *(const bf16x8*)(Bls + (wn + t * 16 + fm) * 64 + slot);
            }
            #pragma unroll
            for (int rt = 0; rt < 4; ++rt)
                #pragma unroll
                for (int ct = 0; ct < 4; ++ct)
                    acc[rt][ct] = __builtin_amdgcn_mfma_f32_16x16x32_bf16(
                        af[rt], bf[ct], acc[rt][ct], 0, 0, 0);
        }
        __syncthreads();
    }
}

// ---------------------------------------------------------------------------
// Kernel A: flat grid of 768 blocks (all co-resident at 3/CU).
// b < 512: KV block (bx=b>>4, hy=b&15). One K-pass stages X+Wk+Wv; shared X
//   frags feed both acck/accv. Epilogue: transpose-restage K,V bf16 into
//   [64][128] swizzled LDS, 16 MFMA/wave kT, write P[bx][hy]. Then ONE
//   acq_rel atomicAdd on cnt[bx]; the 16th arriver reduces P[bx] -> TB[bx].
// b >= 512: Q block (R10 body) -> Q bf16 at QB.
// ---------------------------------------------------------------------------
__global__ __launch_bounds__(256, 3) void qkvkt768(
    const unsigned short* __restrict__ Xb,
    const unsigned short* __restrict__ Wb,
    const float* __restrict__ bq, const float* __restrict__ bk,
    const float* __restrict__ bv,
    unsigned short* __restrict__ qkv,
    float* __restrict__ P,
    unsigned short* __restrict__ TB,
    unsigned* __restrict__ cnt)
{
    __shared__ __align__(16) unsigned short S[16384];   // 32 KB

    const int b    = blockIdx.x;
    const int tid  = threadIdx.x;
    const int w    = tid >> 6;
    const int lane = tid & 63;
    const int quad = lane >> 4;
    const int fm   = lane & 15;
    const int sw8  = fm & 7;
    const int rbase = quad * 4;
    const int srow = lane >> 3;
    const int skc  = ((lane & 7) ^ (lane >> 3)) * 8;

    if (b >= 512) {
        // ---------------- Q path (R10 body) ----------------
        const int idx = b - 512;
        const int m0 = (idx & 31) * 128;
        const int n0 = (idx >> 5) * 128;
        const int wm = (w >> 1) * 64;
        const int wn = (w & 1) * 64;

        f32x4 acc[4][4];
        #pragma unroll
        for (int i = 0; i < 4; ++i)
            #pragma unroll
            for (int j = 0; j < 4; ++j)
                acc[i][j] = f32x4{0.f, 0.f, 0.f, 0.f};

        gemm_loop(Xb, Wb, S, S + 8192, m0, n0, w, lane, acc);

        float bcol[4];
        #pragma unroll
        for (int ct = 0; ct < 4; ++ct) bcol[ct] = bq[n0 + wn + ct * 16 + fm];

        #pragma unroll
        for (int rt = 0; rt < 4; ++rt) {
            #pragma unroll
            for (int ct = 0; ct < 4; ++ct) {
                #pragma unroll
                for (int r = 0; r < 4; ++r) {
                    const int row = m0 + wm + rt * 16 + rbase + r;
                    const int col = n0 + wn + ct * 16 + fm;
                    qkv[(size_t)row * E_DIM + col] = f2b(acc[rt][ct][r] + bcol[ct]);
                }
            }
        }
        return;
    }

    // ---------------- KV path: 128 rows x 64 cols (one head) ----------------
    const int bx = b >> 4;               // row chunk 0..31
    const int hy = b & 15;               // head 0..15
    const int m0 = bx * 128;
    const int n0 = hy * 64;
    const unsigned short* __restrict__ WK = Wb + 1048576;
    const unsigned short* __restrict__ WV = Wb + 2097152;

    unsigned short* Xls = S;             // [128][64] swizzled, 16 KB
    unsigned short* Kls = S + 8192;      // [64][64]  swizzled,  8 KB
    unsigned short* Vls = S + 12288;     // [64][64]  swizzled,  8 KB

    const int wm = w * 32;               // wave's 32 X-rows

    f32x4 acck[2][4], accv[2][4];
    #pragma unroll
    for (int t = 0; t < 2; ++t)
        #pragma unroll
        for (int n = 0; n < 4; ++n) {
            acck[t][n] = f32x4{0.f, 0.f, 0.f, 0.f};
            accv[t][n] = f32x4{0.f, 0.f, 0.f, 0.f};
        }

    for (int k0 = 0; k0 < E_DIM; k0 += 64) {
        #pragma unroll
        for (int c = 0; c < 4; ++c) {
            const int r = w * 32 + c * 8;
            gl_lds16((const void*)(Xb + (size_t)(m0 + r + srow) * E_DIM + k0 + skc),
                     (void*)((char*)Xls + r * 128 + lane * 16));
        }
        #pragma unroll
        for (int c = 0; c < 2; ++c) {
            const int r = w * 16 + c * 8;
            gl_lds16((const void*)(WK + (size_t)(n0 + r + srow) * E_DIM + k0 + skc),
                     (void*)((char*)Kls + r * 128 + lane * 16));
            gl_lds16((const void*)(WV + (size_t)(n0 + r + srow) * E_DIM + k0 + skc),
                     (void*)((char*)Vls + r * 128 + lane * 16));
        }
        __syncthreads();

        #pragma unroll
        for (int kk = 0; kk < 2; ++kk) {
            const int slot = ((kk * 4 + quad) ^ sw8) * 8;
            bf16x8 af[2], bk_[4], bv_[4];
            #pragma unroll
            for (int t = 0; t < 2; ++t)
                af[t] = *(const bf16x8*)(Xls + (wm + t * 16 + fm) * 64 + slot);
            #pragma unroll
            for (int n = 0; n < 4; ++n) {
                bk_[n] = *(const bf16x8*)(Kls + (n * 16 + fm) * 64 + slot);
                bv_[n] = *(const bf16x8*)(Vls + (n * 16 + fm) * 64 + slot);
            }
            #pragma unroll
            for (int t = 0; t < 2; ++t)
                #pragma unroll
                for (int n = 0; n < 4; ++n) {
                    acck[t][n] = __builtin_amdgcn_mfma_f32_16x16x32_bf16(
                        af[t], bk_[n], acck[t][n], 0, 0, 0);
                    accv[t][n] = __builtin_amdgcn_mfma_f32_16x16x32_bf16(
                        af[t], bv_[n], accv[t][n], 0, 0, 0);
                }
        }
        __syncthreads();
    }

    float bcK[4], bcV[4];
    #pragma unroll
    for (int n = 0; n < 4; ++n) {
        bcK[n] = bk[n0 + n * 16 + fm];
        bcV[n] = bv[n0 + n * 16 + fm];
    }

    // ---- kT epilogue: restage K,V transposed+swizzled into S (free now) ----
    unsigned short* Kt = S;              // [64 e][128 r] swizzled, 16 KB
    unsigned short* Vt = S + 8192;       // [64 d][128 r] swizzled, 16 KB

    #pragma unroll
    for (int t = 0; t < 2; ++t)
        #pragma unroll
        for (int n = 0; n < 4; ++n) {
            const int e  = n * 16 + fm;               // local col 0..63
            const int r0 = wm + t * 16 + rbase;       // local row, %4==0
            *(uint2*)(Kt + sw128(e, r0)) = packfrag(acck[t][n], bcK[n]);
            *(uint2*)(Vt + sw128(e, r0)) = packfrag(accv[t][n], bcV[n]);
        }
    __syncthreads();

    // Tpart[d][e] = sum_{r<128} V[r][d]*K[r][e]; wave w: d = w*16..+16
    f32x4 tacc[4];
    #pragma unroll
    for (int n = 0; n < 4; ++n) tacc[n] = f32x4{0.f, 0.f, 0.f, 0.f};
    #pragma unroll
    for (int kk = 0; kk < 4; ++kk) {
        const int slot = (((kk * 4 + quad) ^ sw8) & 15) << 3;
        const bf16x8 af = *(const bf16x8*)(Vt + (w * 16 + fm) * 128 + slot);
        #pragma unroll
        for (int n = 0; n < 4; ++n) {
            const bf16x8 bf = *(const bf16x8*)(Kt + (n * 16 + fm) * 128 + slot);
            tacc[n] = __builtin_amdgcn_mfma_f32_16x16x32_bf16(af, bf, tacc[n], 0, 0, 0);
        }
    }

    float* __restrict__ Pout = P + ((size_t)bx * 16 + hy) * 4096;
    #pragma unroll
    for (int n = 0; n < 4; ++n)
        #pragma unroll
        for (int r = 0; r < 4; ++r)
            Pout[(size_t)(w * 16 + rbase + r) * 64 + n * 16 + fm] = tacc[n][r];

    // ---- last-arriver reduce: 16th block of bx sums P[bx] -> TB[bx] bf16 ----
    // __syncthreads drains every wave's stores (per-wave vmcnt(0) before
    // s_barrier); tid0's fence + acq_rel atomic publishes them agent-wide.
    __syncthreads();
    if (tid == 0) {
        __threadfence();
        const unsigned old = __hip_atomic_fetch_add(
            &cnt[bx], 1u, __ATOMIC_ACQ_REL, __HIP_MEMORY_SCOPE_AGENT);
        ((int*)S)[0] = (old == 15u) ? 1 : 0;
    }
    __syncthreads();
    if (((int*)S)[0]) {
        __threadfence();   // acquire: invalidate stale cache for P reads
        const int d  = tid >> 2;                       // 0..63
        const int e0 = (tid & 3) << 4;                 // 0,16,32,48
        const float* p = P + (size_t)bx * 65536 + (size_t)d * 64 + e0;
        f32x4 s0{0.f,0.f,0.f,0.f}, s1{0.f,0.f,0.f,0.f};
        f32x4 s2{0.f,0.f,0.f,0.f}, s3{0.f,0.f,0.f,0.f};
        #pragma unroll
        for (int c = 0; c < 16; ++c) {
            s0 += *(const f32x4*)(p + (size_t)c * 4096);
            s1 += *(const f32x4*)(p + (size_t)c * 4096 + 4);
            s2 += *(const f32x4*)(p + (size_t)c * 4096 + 8);
            s3 += *(const f32x4*)(p + (size_t)c * 4096 + 12);
        }
        unsigned short* tb = TB + (size_t)bx * 4096 + d * 64 + e0;
        *(uint4*)(tb)     = pack8(s0, s1);
        *(uint4*)(tb + 8) = pack8(s2, s3);
    }
}

// ---------------------------------------------------------------------------
// Kernel C: per block b: i = (b&7) + ((b>>3)&3)*8, sub = b>>5.
// Stage Q[128 rows] + TB[i] (8 KB) via gl_lds16 (R10-verbatim staging),
// then out = 0.125 * Qflat @ T^T (K=64 MFMA mini-GEMM).
// ---------------------------------------------------------------------------
__global__ __launch_bounds__(256, 2) void qT_fused(
    const unsigned short* __restrict__ qkv,
    const unsigned short* __restrict__ TB,
    float* __restrict__ out)
{
    __shared__ __align__(16) unsigned short Als[128 * 64];  // 16 KB: Q rows
    __shared__ __align__(16) unsigned short Bls[64 * 64];   //  8 KB: T rows

    const int b    = blockIdx.x;            // 0..511
    const int i    = (b & 7) + ((b >> 3) & 3) * 8;   // attn block
    const int sub  = b >> 5;                          // 0..15
    const int r0   = (i * 16 + sub) * 128;            // flat Q row base
    const int tid  = threadIdx.x;
    const int w    = tid >> 6;
    const int lane = tid & 63;
    const int quad = lane >> 4;
    const int fm   = lane & 15;
    const int sw8  = fm & 7;

    const unsigned short* __restrict__ Qb = qkv + QB_U + (size_t)r0 * 64;
    const unsigned short* __restrict__ Tb = TB + (size_t)i * 4096;

    const int soff = (lane >> 3) * 64 + (((lane & 7) ^ (lane >> 3)) << 3);
    #pragma unroll
    for (int c = 0; c < 4; ++c)
        gl_lds16((const void*)(Qb + (w * 4 + c) * 512 + soff),
                 (void*)((char*)Als + (w * 4 + c) * 1024));
    #pragma unroll
    for (int c = 0; c < 2; ++c)
        gl_lds16((const void*)(Tb + (w * 2 + c) * 512 + soff),
                 (void*)((char*)Bls + (w * 2 + c) * 1024));
    __syncthreads();

    // qT mini-GEMM
    bf16x8 af[2][2], bf[4][2];
    #pragma unroll
    for (int mt = 0; mt < 2; ++mt)
        #pragma unroll
        for (int kk = 0; kk < 2; ++kk)
            af[mt][kk] = *(const bf16x8*)(Als + (w * 32 + mt * 16 + fm) * 64
                                          + (((kk * 4 + quad) ^ sw8) << 3));
    #pragma unroll
    for (int nt = 0; nt < 4; ++nt)
        #pragma unroll
        for (int kk = 0; kk < 2; ++kk)
            bf[nt][kk] = *(const bf16x8*)(Bls + (nt * 16 + fm) * 64
                                          + (((kk * 4 + quad) ^ sw8) << 3));

    f32x4 acc[2][4];
    #pragma unroll
    for (int mt = 0; mt < 2; ++mt)
        #pragma unroll
        for (int nt = 0; nt < 4; ++nt)
            acc[mt][nt] = f32x4{0.f, 0.f, 0.f, 0.f};

    #pragma unroll
    for (int kk = 0; kk < 2; ++kk)
        #pragma unroll
        for (int mt = 0; mt < 2; ++mt)
            #pragma unroll
            for (int nt = 0; nt < 4; ++nt)
                acc[mt][nt] = __builtin_amdgcn_mfma_f32_16x16x32_bf16(
                    af[mt][kk], bf[nt][kk], acc[mt][nt], 0, 0, 0);

    const int rbase = (lane >> 4) * 4;
    #pragma unroll
    for (int mt = 0; mt < 2; ++mt) {
        #pragma unroll
        for (int nt = 0; nt < 4; ++nt) {
            #pragma unroll
            for (int r = 0; r < 4; ++r) {
                const int row = r0 + w * 32 + mt * 16 + rbase + r;
                const int col = nt * 16 + fm;
                out[(size_t)row * 64 + col] = 0.125f * acc[mt][nt][r];
            }
        }
    }
}

extern "C" void kernel_launch(void* const* d_in, const int* in_sizes, int n_in,
                              void* d_out, int out_size, void* d_ws, size_t ws_size,
                              hipStream_t stream)
{
    const float* x  = (const float*)d_in[0];
    const float* Wq = (const float*)d_in[1];
    const float* bq = (const float*)d_in[2];
    const float* Wk = (const float*)d_in[3];
    const float* bk = (const float*)d_in[4];
    const float* Wv = (const float*)d_in[5];
    const float* bv = (const float*)d_in[6];
    float* wsf = (float*)d_ws;
    unsigned short* wsu = (unsigned short*)d_ws;
    float* out = (float*)d_out;
    unsigned* cnt = (unsigned*)(wsf + BAR_F);

    dim3 gCvt(512, 7);
    cvt_bf16<<<gCvt, 256, 0, stream>>>(x, Wq, Wk, Wv, wsu + XB_U, cnt);

    qkvkt768<<<768, 256, 0, stream>>>(wsu + XB_U, wsu + WB_U,
                                      bq, bk, bv, wsu, wsf + P_F,
                                      wsu + TB_U, cnt);

    qT_fused<<<512, 256, 0, stream>>>(wsu, wsu + TB_U, out);
}

// Round 9
// 119.924 us; speedup vs baseline: 1.4711x; 1.4711x over previous
//
#include <hip/hip_runtime.h>
#include <hip/hip_bf16.h>

// out = (Q K^T) V * scale, softmax discarded => associativity:
//   out_i = Q_i @ (K_i^T @ V_i) * scale over 32 blocks of 2048 flat rows of
//   the (65536,64) view of the (4096,1024) projections.
// R19 = R17 (124.9us, passing) + P stored as bf16 (halves qT's redundant
// P-read traffic 134->67 MB and the P write 8->4 MB; one extra bf16 rounding
// per chunk before the 16-chunk sum, ~+0.05 absmax vs 1.4 threshold).
// NO cross-block sync anywhere (R12/R13/R18 all proved it poison here).
// 3 kernels: cvt -> qkvkt768 (512 KV-fused + 256 Q, all 3/CU co-resident)
//           -> qT_fused (redundant bf16 P-reduce prologue + K=64 mini-GEMM).

#define E_DIM 1024
#define N_ROWS 4096

typedef __attribute__((ext_vector_type(8))) short bf16x8;
typedef __attribute__((ext_vector_type(4))) float f32x4;

// ---- ws layout (shorts) ----
// QB 0 (Q bf16, 8.4MB)  XB 12582912  WB 16777216 (ends 19922944)
// PB 20971520 (32 blk x 16 chunks x 4096 bf16 = 4 MB, bytes 41.9..46.1MB)
#define QB_U 0
#define XB_U 12582912
#define WB_U 16777216
#define PB_U 20971520

__device__ __forceinline__ unsigned short f2b(float f) {
    union { float f; unsigned int i; } c; c.f = f;
    unsigned int r = c.i + 0x7FFFu + ((c.i >> 16) & 1u);   // RNE (finite data)
    return (unsigned short)(r >> 16);
}

__device__ __forceinline__ uint4 pack8(const f32x4 a, const f32x4 b) {
    uint4 o;
    o.x = (unsigned)f2b(a[0]) | ((unsigned)f2b(a[1]) << 16);
    o.y = (unsigned)f2b(a[2]) | ((unsigned)f2b(a[3]) << 16);
    o.z = (unsigned)f2b(b[0]) | ((unsigned)f2b(b[1]) << 16);
    o.w = (unsigned)f2b(b[2]) | ((unsigned)f2b(b[3]) << 16);
    return o;
}

// unpack 4 packed bf16 (two u32 words, low-short first) -> f32x4
__device__ __forceinline__ f32x4 b2f4(unsigned a, unsigned b) {
    union { unsigned u; float f; } e0, e1, e2, e3;
    e0.u = a << 16; e1.u = a & 0xffff0000u;
    e2.u = b << 16; e3.u = b & 0xffff0000u;
    return f32x4{e0.f, e1.f, e2.f, e3.f};
}

// pack 4 acc rows + bias into 4 bf16 (one uint2)
__device__ __forceinline__ uint2 packfrag(const f32x4 a, float b) {
    uint2 v;
    v.x = (unsigned)f2b(a[0] + b) | ((unsigned)f2b(a[1] + b) << 16);
    v.y = (unsigned)f2b(a[2] + b) | ((unsigned)f2b(a[3] + b) << 16);
    return v;
}

typedef __attribute__((address_space(1))) const void* gptr_t;
typedef __attribute__((address_space(3))) void* lptr_t;
__device__ __forceinline__ void gl_lds16(const void* g, void* l) {
    __builtin_amdgcn_global_load_lds((gptr_t)g, (lptr_t)l, 16, 0, 0);
}

// swizzled index into a [row][64] LDS tile (8 slots of 8 elems per row)
__device__ __forceinline__ int sw_idx(int row, int r) {
    return row * 64 + (((((r) >> 3) & 7) ^ (row & 7)) << 3) + (r & 7);
}

// swizzled index into a [row][128] LDS tile (16 slots of 8; XOR low 3 slot bits)
__device__ __forceinline__ int sw128(int row, int r) {
    return row * 128 + ((((r >> 3) ^ (row & 7)) & 15) << 3) + (r & 7);
}

// ---------------------------------------------------------------------------
// Kernel 0: fp32 -> bf16 convert: x (4 MB-segs) + Wq/Wk/Wv.
// ---------------------------------------------------------------------------
__global__ __launch_bounds__(256) void cvt_bf16(
    const float* __restrict__ x,  const float* __restrict__ wq,
    const float* __restrict__ wk, const float* __restrict__ wv,
    unsigned short* __restrict__ dst0)
{
    const int seg = blockIdx.y;
    const float* __restrict__ src;
    unsigned short* __restrict__ dst;
    if (seg < 4) { src = x + (size_t)seg * 1048576; dst = dst0 + (size_t)seg * 1048576; }
    else {
        src = (seg == 4) ? wq : (seg == 5) ? wk : wv;
        dst = dst0 + 4194304 + (size_t)(seg - 4) * 1048576;
    }
    const int i = blockIdx.x * 256 + threadIdx.x;   // 0..131071
    const float4 a = *(const float4*)(src + (size_t)i * 8);
    const float4 b = *(const float4*)(src + (size_t)i * 8 + 4);
    uint4 o;
    o.x = (unsigned)f2b(a.x) | ((unsigned)f2b(a.y) << 16);
    o.y = (unsigned)f2b(a.z) | ((unsigned)f2b(a.w) << 16);
    o.z = (unsigned)f2b(b.x) | ((unsigned)f2b(b.y) << 16);
    o.w = (unsigned)f2b(b.z) | ((unsigned)f2b(b.w) << 16);
    *(uint4*)(dst + (size_t)i * 8) = o;
}

// ---------------------------------------------------------------------------
// One full 128x128 K=1024 GEMM accumulation loop (R10 body). acc += Xb@W^T.
// ---------------------------------------------------------------------------
__device__ __forceinline__ void gemm_loop(
    const unsigned short* __restrict__ Xb, const unsigned short* __restrict__ W,
    unsigned short* Als, unsigned short* Bls,
    int m0, int n0, int w, int lane, f32x4 (&acc)[4][4])
{
    const int quad = lane >> 4;
    const int fm   = lane & 15;
    const int sw8  = fm & 7;
    const int srow = lane >> 3;                       // 0..7
    const int skc  = ((lane & 7) ^ (lane >> 3)) * 8;  // swizzled global chunk
    const int wm = (w >> 1) * 64;
    const int wn = (w & 1) * 64;

    for (int k0 = 0; k0 < E_DIM; k0 += 64) {
        #pragma unroll
        for (int c = 0; c < 4; ++c) {
            const int r = w * 32 + c * 8;
            gl_lds16((const void*)(Xb + (size_t)(m0 + r + srow) * E_DIM + k0 + skc),
                     (void*)((char*)Als + r * 128 + lane * 16));
            gl_lds16((const void*)(W + (size_t)(n0 + r + srow) * E_DIM + k0 + skc),
                     (void*)((char*)Bls + r * 128 + lane * 16));
        }
        __syncthreads();

        #pragma unroll
        for (int kk = 0; kk < 2; ++kk) {
            const int slot = ((kk * 4 + quad) ^ sw8) * 8;
            bf16x8 af[4], bf[4];
            #pragma unroll
            for (int t = 0; t < 4; ++t) {
                af[t] = *(const bf16x8*)(Als + (wm + t * 16 + fm) * 64 + slot);
                bf[t] = *(const bf16x8*)(Bls + (wn + t * 16 + fm) * 64 + slot);
            }
            #pragma unroll
            for (int rt = 0; rt < 4; ++rt)
                #pragma unroll
                for (int ct = 0; ct < 4; ++ct)
                    acc[rt][ct] = __builtin_amdgcn_mfma_f32_16x16x32_bf16(
                        af[rt], bf[ct], acc[rt][ct], 0, 0, 0);
        }
        __syncthreads();
    }
}

// ---------------------------------------------------------------------------
// Kernel A: flat grid of 768 blocks (all co-resident at 3/CU).
// b < 512: KV block (bx=b>>4, hy=b&15). One K-pass stages X+Wk+Wv; shared X
//   frags feed both acck/accv. Epilogue: transpose-restage K,V bf16 into
//   [64][128] swizzled LDS, 16 MFMA/wave kT, write P[bx][hy] bf16.
// b >= 512: Q block (R10 body) -> Q bf16 at QB.
// ---------------------------------------------------------------------------
__global__ __launch_bounds__(256, 3) void qkvkt768(
    const unsigned short* __restrict__ Xb,
    const unsigned short* __restrict__ Wb,
    const float* __restrict__ bq, const float* __restrict__ bk,
    const float* __restrict__ bv,
    unsigned short* __restrict__ qkv,
    unsigned short* __restrict__ Pb)
{
    __shared__ __align__(16) unsigned short S[16384];   // 32 KB

    const int b    = blockIdx.x;
    const int tid  = threadIdx.x;
    const int w    = tid >> 6;
    const int lane = tid & 63;
    const int quad = lane >> 4;
    const int fm   = lane & 15;
    const int sw8  = fm & 7;
    const int rbase = quad * 4;
    const int srow = lane >> 3;
    const int skc  = ((lane & 7) ^ (lane >> 3)) * 8;

    if (b >= 512) {
        // ---------------- Q path (R10 body) ----------------
        const int idx = b - 512;
        const int m0 = (idx & 31) * 128;
        const int n0 = (idx >> 5) * 128;
        const int wm = (w >> 1) * 64;
        const int wn = (w & 1) * 64;

        f32x4 acc[4][4];
        #pragma unroll
        for (int i = 0; i < 4; ++i)
            #pragma unroll
            for (int j = 0; j < 4; ++j)
                acc[i][j] = f32x4{0.f, 0.f, 0.f, 0.f};

        gemm_loop(Xb, Wb, S, S + 8192, m0, n0, w, lane, acc);

        float bcol[4];
        #pragma unroll
        for (int ct = 0; ct < 4; ++ct) bcol[ct] = bq[n0 + wn + ct * 16 + fm];

        #pragma unroll
        for (int rt = 0; rt < 4; ++rt) {
            #pragma unroll
            for (int ct = 0; ct < 4; ++ct) {
                #pragma unroll
                for (int r = 0; r < 4; ++r) {
                    const int row = m0 + wm + rt * 16 + rbase + r;
                    const int col = n0 + wn + ct * 16 + fm;
                    qkv[(size_t)row * E_DIM + col] = f2b(acc[rt][ct][r] + bcol[ct]);
                }
            }
        }
        return;
    }

    // ---------------- KV path: 128 rows x 64 cols (one head) ----------------
    const int bx = b >> 4;               // row chunk 0..31
    const int hy = b & 15;               // head 0..15
    const int m0 = bx * 128;
    const int n0 = hy * 64;
    const unsigned short* __restrict__ WK = Wb + 1048576;
    const unsigned short* __restrict__ WV = Wb + 2097152;

    unsigned short* Xls = S;             // [128][64] swizzled, 16 KB
    unsigned short* Kls = S + 8192;      // [64][64]  swizzled,  8 KB
    unsigned short* Vls = S + 12288;     // [64][64]  swizzled,  8 KB

    const int wm = w * 32;               // wave's 32 X-rows

    f32x4 acck[2][4], accv[2][4];
    #pragma unroll
    for (int t = 0; t < 2; ++t)
        #pragma unroll
        for (int n = 0; n < 4; ++n) {
            acck[t][n] = f32x4{0.f, 0.f, 0.f, 0.f};
            accv[t][n] = f32x4{0.f, 0.f, 0.f, 0.f};
        }

    for (int k0 = 0; k0 < E_DIM; k0 += 64) {
        #pragma unroll
        for (int c = 0; c < 4; ++c) {
            const int r = w * 32 + c * 8;
            gl_lds16((const void*)(Xb + (size_t)(m0 + r + srow) * E_DIM + k0 + skc),
                     (void*)((char*)Xls + r * 128 + lane * 16));
        }
        #pragma unroll
        for (int c = 0; c < 2; ++c) {
            const int r = w * 16 + c * 8;
            gl_lds16((const void*)(WK + (size_t)(n0 + r + srow) * E_DIM + k0 + skc),
                     (void*)((char*)Kls + r * 128 + lane * 16));
            gl_lds16((const void*)(WV + (size_t)(n0 + r + srow) * E_DIM + k0 + skc),
                     (void*)((char*)Vls + r * 128 + lane * 16));
        }
        __syncthreads();

        #pragma unroll
        for (int kk = 0; kk < 2; ++kk) {
            const int slot = ((kk * 4 + quad) ^ sw8) * 8;
            bf16x8 af[2], bk_[4], bv_[4];
            #pragma unroll
            for (int t = 0; t < 2; ++t)
                af[t] = *(const bf16x8*)(Xls + (wm + t * 16 + fm) * 64 + slot);
            #pragma unroll
            for (int n = 0; n < 4; ++n) {
                bk_[n] = *(const bf16x8*)(Kls + (n * 16 + fm) * 64 + slot);
                bv_[n] = *(const bf16x8*)(Vls + (n * 16 + fm) * 64 + slot);
            }
            #pragma unroll
            for (int t = 0; t < 2; ++t)
                #pragma unroll
                for (int n = 0; n < 4; ++n) {
                    acck[t][n] = __builtin_amdgcn_mfma_f32_16x16x32_bf16(
                        af[t], bk_[n], acck[t][n], 0, 0, 0);
                    accv[t][n] = __builtin_amdgcn_mfma_f32_16x16x32_bf16(
                        af[t], bv_[n], accv[t][n], 0, 0, 0);
                }
        }
        __syncthreads();
    }

    float bcK[4], bcV[4];
    #pragma unroll
    for (int n = 0; n < 4; ++n) {
        bcK[n] = bk[n0 + n * 16 + fm];
        bcV[n] = bv[n0 + n * 16 + fm];
    }

    // ---- kT epilogue: restage K,V transposed+swizzled into S (free now) ----
    unsigned short* Kt = S;              // [64 e][128 r] swizzled, 16 KB
    unsigned short* Vt = S + 8192;       // [64 d][128 r] swizzled, 16 KB

    #pragma unroll
    for (int t = 0; t < 2; ++t)
        #pragma unroll
        for (int n = 0; n < 4; ++n) {
            const int e  = n * 16 + fm;               // local col 0..63
            const int r0 = wm + t * 16 + rbase;       // local row, %4==0
            *(uint2*)(Kt + sw128(e, r0)) = packfrag(acck[t][n], bcK[n]);
            *(uint2*)(Vt + sw128(e, r0)) = packfrag(accv[t][n], bcV[n]);
        }
    __syncthreads();

    // Tpart[d][e] = sum_{r<128} V[r][d]*K[r][e]; wave w: d = w*16..+16
    f32x4 tacc[4];
    #pragma unroll
    for (int n = 0; n < 4; ++n) tacc[n] = f32x4{0.f, 0.f, 0.f, 0.f};
    #pragma unroll
    for (int kk = 0; kk < 4; ++kk) {
        const int slot = (((kk * 4 + quad) ^ sw8) & 15) << 3;
        const bf16x8 af = *(const bf16x8*)(Vt + (w * 16 + fm) * 128 + slot);
        #pragma unroll
        for (int n = 0; n < 4; ++n) {
            const bf16x8 bf = *(const bf16x8*)(Kt + (n * 16 + fm) * 128 + slot);
            tacc[n] = __builtin_amdgcn_mfma_f32_16x16x32_bf16(af, bf, tacc[n], 0, 0, 0);
        }
    }

    // P chunk stored bf16 [d][e] (scalar short stores; epilogue-only cost)
    unsigned short* __restrict__ Pout = Pb + ((size_t)bx * 16 + hy) * 4096;
    #pragma unroll
    for (int n = 0; n < 4; ++n)
        #pragma unroll
        for (int r = 0; r < 4; ++r)
            Pout[(size_t)(w * 16 + rbase + r) * 64 + n * 16 + fm] = f2b(tacc[n][r]);
}

// ---------------------------------------------------------------------------
// Kernel C: per block b: i = (b&7) + ((b>>3)&3)*8, sub = b>>5.
// Redundant reduce of P[i] (16 bf16 chunks, 128 KB) -> Tls bf16 swizzled;
// Q staged async under it; out = 0.125 * Qflat @ T^T (K=64 mini-GEMM).
// ---------------------------------------------------------------------------
__global__ __launch_bounds__(256, 2) void qT_fused(
    const unsigned short* __restrict__ qkv,
    const unsigned short* __restrict__ Pb,
    float* __restrict__ out)
{
    __shared__ __align__(16) unsigned short Als[128 * 64];  // 16 KB: Q rows
    __shared__ __align__(16) unsigned short Tls[64 * 64];   //  8 KB: T[d][e]

    const int b    = blockIdx.x;            // 0..511
    const int i    = (b & 7) + ((b >> 3) & 3) * 8;   // attn block
    const int sub  = b >> 5;                          // 0..15
    const int r0   = (i * 16 + sub) * 128;            // flat Q row base
    const int tid  = threadIdx.x;
    const int w    = tid >> 6;
    const int lane = tid & 63;
    const int quad = lane >> 4;
    const int fm   = lane & 15;
    const int sw8  = fm & 7;

    const unsigned short* __restrict__ Qb = qkv + QB_U + (size_t)r0 * 64;

    // issue Q staging first (async via vmcnt; hides under the P reduce)
    const int soff = (lane >> 3) * 64 + (((lane & 7) ^ (lane >> 3)) << 3);
    #pragma unroll
    for (int c = 0; c < 4; ++c)
        gl_lds16((const void*)(Qb + (w * 4 + c) * 512 + soff),
                 (void*)((char*)Als + (w * 4 + c) * 1024));

    // redundant per-block reduce of P[i] (16 bf16 chunks) -> Tls bf16 swizzled
    {
        const int d  = tid >> 2;                       // 0..63
        const int e0 = (tid & 3) << 4;                 // 0,16,32,48
        const unsigned short* p = Pb + (size_t)i * 65536 + (size_t)d * 64 + e0;
        f32x4 s0{0.f,0.f,0.f,0.f}, s1{0.f,0.f,0.f,0.f};
        f32x4 s2{0.f,0.f,0.f,0.f}, s3{0.f,0.f,0.f,0.f};
        #pragma unroll
        for (int c = 0; c < 16; ++c) {
            const uint4 u0 = *(const uint4*)(p + (size_t)c * 4096);      // e0..+7
            const uint4 u1 = *(const uint4*)(p + (size_t)c * 4096 + 8);  // e0+8..+15
            s0 += b2f4(u0.x, u0.y);
            s1 += b2f4(u0.z, u0.w);
            s2 += b2f4(u1.x, u1.y);
            s3 += b2f4(u1.z, u1.w);
        }
        const int c0 = e0 >> 3;                        // even slot index
        *(uint4*)(Tls + d * 64 + ((c0 ^ (d & 7)) << 3))       = pack8(s0, s1);
        *(uint4*)(Tls + d * 64 + (((c0 + 1) ^ (d & 7)) << 3)) = pack8(s2, s3);
    }
    __syncthreads();   // drains gl_lds16 (vmcnt) + orders Tls writes

    // qT mini-GEMM
    bf16x8 af[2][2], bf[4][2];
    #pragma unroll
    for (int mt = 0; mt < 2; ++mt)
        #pragma unroll
        for (int kk = 0; kk < 2; ++kk)
            af[mt][kk] = *(const bf16x8*)(Als + (w * 32 + mt * 16 + fm) * 64
                                          + (((kk * 4 + quad) ^ sw8) << 3));
    #pragma unroll
    for (int nt = 0; nt < 4; ++nt)
        #pragma unroll
        for (int kk = 0; kk < 2; ++kk)
            bf[nt][kk] = *(const bf16x8*)(Tls + (nt * 16 + fm) * 64
                                          + (((kk * 4 + quad) ^ sw8) << 3));

    f32x4 acc[2][4];
    #pragma unroll
    for (int mt = 0; mt < 2; ++mt)
        #pragma unroll
        for (int nt = 0; nt < 4; ++nt)
            acc[mt][nt] = f32x4{0.f, 0.f, 0.f, 0.f};

    #pragma unroll
    for (int kk = 0; kk < 2; ++kk)
        #pragma unroll
        for (int mt = 0; mt < 2; ++mt)
            #pragma unroll
            for (int nt = 0; nt < 4; ++nt)
                acc[mt][nt] = __builtin_amdgcn_mfma_f32_16x16x32_bf16(
                    af[mt][kk], bf[nt][kk], acc[mt][nt], 0, 0, 0);

    const int rbase = (lane >> 4) * 4;
    #pragma unroll
    for (int mt = 0; mt < 2; ++mt) {
        #pragma unroll
        for (int nt = 0; nt < 4; ++nt) {
            #pragma unroll
            for (int r = 0; r < 4; ++r) {
                const int row = r0 + w * 32 + mt * 16 + rbase + r;
                const int col = nt * 16 + fm;
                out[(size_t)row * 64 + col] = 0.125f * acc[mt][nt][r];
            }
        }
    }
}

extern "C" void kernel_launch(void* const* d_in, const int* in_sizes, int n_in,
                              void* d_out, int out_size, void* d_ws, size_t ws_size,
                              hipStream_t stream)
{
    const float* x  = (const float*)d_in[0];
    const float* Wq = (const float*)d_in[1];
    const float* bq = (const float*)d_in[2];
    const float* Wk = (const float*)d_in[3];
    const float* bk = (const float*)d_in[4];
    const float* Wv = (const float*)d_in[5];
    const float* bv = (const float*)d_in[6];
    unsigned short* wsu = (unsigned short*)d_ws;
    float* out = (float*)d_out;

    dim3 gCvt(512, 7);
    cvt_bf16<<<gCvt, 256, 0, stream>>>(x, Wq, Wk, Wv, wsu + XB_U);

    qkvkt768<<<768, 256, 0, stream>>>(wsu + XB_U, wsu + WB_U,
                                      bq, bk, bv, wsu, wsu + PB_U);

    qT_fused<<<512, 256, 0, stream>>>(wsu, wsu + PB_U, out);
}